// Round 1
// baseline (1467.302 us; speedup 1.0000x reference)
//
#include <hip/hip_runtime.h>
#include <math.h>

#define Bb 4
#define Tt 2048
#define Dd 256
#define SRr 128
#define Rr 8
#define NA 8
#define NV 16
#define Lf 4096
#define LOG2L 12
#define EPSf 1e-5f
#define PI_D 3.14159265358979323846

// ---- workspace layout (floats) ----
#define OFF_TWR   0
#define OFF_TWI   (OFF_TWR + Lf/2)
#define OFF_PRE   (OFF_TWI + Lf/2)           // NV*Tt*2
#define OFF_POST  (OFF_PRE + NV*Tt*2)        // NV*Tt*2
#define OFF_H     (OFF_POST + NV*Tt*2)       // NV*Lf*2
#define OFF_WINT  (OFF_H + NV*Lf*2)          // Dd*SRr
#define OFF_WOUTT (OFF_WINT + Dd*SRr)        // SRr*Dd
#define OFF_WOT   (OFF_WOUTT + SRr*Dd)       // Dd*Dd
#define OFF_WTAB  (OFF_WOT + Dd*Dd)          // NA*Bb*Tt
#define OFF_ESUM  (OFF_WTAB + NA*Bb*Tt)      // NA*Bb*Tt
#define OFF_V     (OFF_ESUM + NA*Bb*Tt)      // Bb*Dd*Rr
#define OFF_M     (OFF_V + Bb*Dd*Rr)         // Bb*Dd*Rr
#define OFF_YT    (OFF_M + Bb*Dd*Rr)         // Bb*Rr*Tt
#define OFF_YACC  (OFF_YT + Bb*Rr*Tt)        // Bb*Rr*Tt
#define OFF_U     (OFF_YACC + Bb*Rr*Tt)      // Bb*Tt*SRr
#define OFF_S     (OFF_U + Bb*Tt*SRr)        // Bb*Tt*Dd
#define OFF_XPT   (OFF_S + Bb*Tt*Dd)         // Bb*Tt*Dd (as [B,D,T])
#define OFF_HBUF  (OFF_XPT + Bb*Tt*Dd)       // Bb*Tt*Dd

__device__ __forceinline__ int brev12(int i){ return (int)(__brev((unsigned)i) >> 20); }

__device__ float block_reduce_sum(float v, float* red, int tid){
  __syncthreads();
  red[tid] = v; __syncthreads();
  for (int s = 128; s > 0; s >>= 1){
    if (tid < s) red[tid] += red[tid + s];
    __syncthreads();
  }
  return red[0];
}

// replicate frft_time's parameter math in double (matches Python float math)
__device__ void variant_params(int v, double& s_, double& c_){
  double step = (2.99 - 0.15) / 7.0;
  int idx = v & 7;
  double alpha = (idx == 7) ? 2.99 : (0.15 + (double)idx * step);
  if (v >= 8) alpha = -alpha;
  double a = fmod(alpha + PI_D, 2.0 * PI_D);
  if (a < 0.0) a += 2.0 * PI_D;
  a -= PI_D;
  double sa = sin(a);
  s_ = ((sa >= 0.0) ? 1.0 : -1.0) / fmax(1e-7, fabs(sa));
  c_ = cos(a) / fmax(1e-7, sa);   // NOTE: reference quirk — not abs(sa)!
}

// radix-2 DIT FFT, data pre-permuted to bit-reversed order, 256 threads.
__device__ void fft_lds(float* re, float* im, const float* twr, const float* twi,
                        bool inv, int tid){
  for (int st = 1; st <= LOG2L; ++st){
    __syncthreads();
    int half = 1 << (st - 1);
    int stepT = Lf >> st;
    for (int j = tid; j < Lf/2; j += 256){
      int pos = j & (half - 1);
      int i0 = ((j >> (st - 1)) << st) + pos;
      int i1 = i0 + half;
      float wr = twr[pos * stepT];
      float wi = twi[pos * stepT];
      if (inv) wi = -wi;
      float br = re[i1], bi = im[i1];
      float tr = br * wr - bi * wi;
      float ti = br * wi + bi * wr;
      float ar = re[i0], ai = im[i0];
      re[i0] = ar + tr; im[i0] = ai + ti;
      re[i1] = ar - tr; im[i1] = ai - ti;
    }
  }
  __syncthreads();
}

__device__ void mulH_and_bitrev(float* re, float* im, const float* Hv, int tid){
  // caller guarantees fft_lds's trailing sync already happened
  #pragma unroll
  for (int k = 0; k < 16; ++k){
    int i = tid + k * 256;
    float hr = Hv[i*2], hi = Hv[i*2+1];
    float gr = re[i], gi = im[i];
    re[i] = gr*hr - gi*hi;
    im[i] = gr*hi + gi*hr;
  }
  __syncthreads();
  #pragma unroll
  for (int k = 0; k < 16; ++k){
    int i = tid + k * 256;
    int rb = brev12(i);
    if (i < rb){
      float a = re[i]; re[i] = re[rb]; re[rb] = a;
      float b = im[i]; im[i] = im[rb]; im[rb] = b;
    }
  }
}

// ---------------- setup kernels ----------------
__global__ void k_twiddle(float* ws){
  for (int k = threadIdx.x; k < Lf/2; k += 256){
    double ang = -2.0 * PI_D * (double)k / (double)Lf;
    ws[OFF_TWR + k] = (float)cos(ang);
    ws[OFF_TWI + k] = (float)sin(ang);
  }
}

__global__ void k_tables(float* ws){
  int v = blockIdx.x;
  double s_, c_;
  variant_params(v, s_, c_);
  double dt = 2.0 / (double)(Tt - 1);
  // pref = sqrt(complex64(1 - i*c)) — c cast to float first, like np.complex64
  double cf = (double)(float)c_;
  double rmag = sqrt(1.0 + cf * cf);
  double pr = sqrt((rmag + 1.0) * 0.5);
  double pim = ((cf >= 0.0) ? -1.0 : 1.0) * sqrt(fmax(0.0, (rmag - 1.0) * 0.5));
  double cps = PI_D * (c_ + s_);
  double sc = dt / (double)Lf;   // fold dt and 1/L (ifft scale) into post
  for (int k = threadIdx.x; k < Tt; k += 256){
    double t = (k == Tt - 1) ? 1.0 : ((double)k * dt - 1.0);
    double th = cps * (t * t);
    double cr = cos(th), ci = sin(th);
    ws[OFF_PRE  + (v*Tt + k)*2 + 0] = (float)cr;
    ws[OFF_PRE  + (v*Tt + k)*2 + 1] = (float)ci;
    ws[OFF_POST + (v*Tt + k)*2 + 0] = (float)((pr*cr - pim*ci) * sc);
    ws[OFF_POST + (v*Tt + k)*2 + 1] = (float)((pr*ci + pim*cr) * sc);
  }
}

__global__ __launch_bounds__(256) void k_hfft(float* ws){
  __shared__ float lre[Lf], lim[Lf];
  int v = blockIdx.x, tid = threadIdx.x;
  double s_, c_;
  variant_params(v, s_, c_);
  double dt = 2.0 / (double)(Tt - 1);
  for (int i = tid; i < Lf; i += 256){ lre[i] = 0.f; lim[i] = 0.f; }
  __syncthreads();
  double ns = -(PI_D * s_);
  for (int mm = tid; mm < 2*Tt - 1; mm += 256){
    int m = mm - (Tt - 1);
    double md = (double)m * dt;
    double th = ns * (md * md);
    int j = (m + Lf) & (Lf - 1);
    int jb = brev12(j);
    lre[jb] = (float)cos(th);
    lim[jb] = (float)sin(th);
  }
  fft_lds(lre, lim, ws + OFF_TWR, ws + OFF_TWI, false, tid);
  for (int i = tid; i < Lf; i += 256){
    ws[OFF_H + (v*Lf + i)*2 + 0] = lre[i];
    ws[OFF_H + (v*Lf + i)*2 + 1] = lim[i];
  }
}

__global__ void k_transpose(const float* Win, const float* Wout, const float* Wo, float* ws){
  int id = blockIdx.x * 256 + threadIdx.x;   // 65536 threads
  { int d = id & (Dd-1); int k = id >> 8; ws[OFF_WOT + id] = Wo[d*Dd + k]; }
  if (id < Dd*SRr){
    int c = id & (SRr-1); int k = id >> 7;            // WinT[k*SR+c] = Win[c*D+k]
    ws[OFF_WINT + id] = Win[c*Dd + k];
    int d2 = id & (Dd-1); int k2 = id >> 8;           // WoutT[k*D+d] = Wout[d*SR+k]
    ws[OFF_WOUTT + id] = Wout[d2*SRr + k2];
  }
}

// ---------------- shift + xprime ----------------
__global__ void k_u(const float* x, float* ws){
  __shared__ float xr[Dd];
  int bt = blockIdx.x, tid = threadIdx.x;  // 128 threads
  xr[tid] = x[bt*Dd + tid];
  xr[tid + 128] = x[bt*Dd + tid + 128];
  __syncthreads();
  const float* WT = ws + OFF_WINT;
  float acc = 0.f;
  for (int k = 0; k < Dd; ++k) acc = fmaf(xr[k], WT[k*SRr + tid], acc);
  float u = 0.5f * acc * (1.0f + erff(acc * 0.70710678118654752f));
  ws[OFF_U + bt*SRr + tid] = u;
}

__global__ void k_sxp(const float* x, const float* bsh, float* ws){
  __shared__ float ur[SRr];
  int bt = blockIdx.x, tid = threadIdx.x;  // 256 threads
  if (tid < SRr) ur[tid] = ws[OFF_U + bt*SRr + tid];
  __syncthreads();
  const float* WT = ws + OFF_WOUTT;
  float acc = bsh[tid];
  for (int k = 0; k < SRr; ++k) acc = fmaf(ur[k], WT[k*Dd + tid], acc);
  float xv = x[bt*Dd + tid];
  float anc = (tid == 0) ? 1.0f : 0.0f;
  float xp = xv - anc + acc;
  ws[OFF_S + bt*Dd + tid] = acc;
  int b = bt >> 11, t = bt & (Tt - 1);
  ws[OFF_XPT + (b*Dd + tid)*Tt + t] = xp;
}

// ---------------- FrFT energy weights ----------------
__global__ __launch_bounds__(256) void k_weights(float* ws){
  __shared__ float lre[Lf], lim[Lf];
  int tid = threadIdx.x;
  int chunk = blockIdx.x, b = blockIdx.y, z = blockIdx.z;
  const float* pre  = ws + OFF_PRE  + z*Tt*2;
  const float* post = ws + OFF_POST + z*Tt*2;
  const float* Hv   = ws + OFF_H    + z*Lf*2;
  const float* twr = ws + OFF_TWR; const float* twi = ws + OFF_TWI;
  float e[8];
  #pragma unroll
  for (int k = 0; k < 8; ++k) e[k] = 0.f;
  for (int cc = 0; cc < 8; ++cc){
    int c = chunk*8 + cc;
    const float* xcol = ws + OFF_XPT + (b*Dd + c)*Tt;
    __syncthreads();
    #pragma unroll
    for (int k = 0; k < 8; ++k){
      int t = tid + k*256;
      float xv = xcol[t];
      int jb = brev12(t);
      lre[jb] = xv * pre[t*2];
      lim[jb] = xv * pre[t*2+1];
      int t2 = t + Tt;
      int jb2 = brev12(t2);
      lre[jb2] = 0.f; lim[jb2] = 0.f;
    }
    fft_lds(lre, lim, twr, twi, false, tid);
    mulH_and_bitrev(lre, lim, Hv, tid);
    fft_lds(lre, lim, twr, twi, true, tid);
    #pragma unroll
    for (int k = 0; k < 8; ++k){
      int t = tid + k*256;
      int j = (Tt - 1) + t;
      float cr = lre[j], ci = lim[j];
      float por = post[t*2], poi = post[t*2+1];
      e[k] += (por*por + poi*poi) * (cr*cr + ci*ci);
    }
  }
  float* Ez = ws + OFF_ESUM + (z*Bb + b)*Tt;
  #pragma unroll
  for (int k = 0; k < 8; ++k) atomicAdd(&Ez[tid + k*256], e[k]);
}

__global__ void k_wnorm(float* ws){
  __shared__ float red[256];
  int b = blockIdx.x, z = blockIdx.y, tid = threadIdx.x;
  const float* Ez = ws + OFF_ESUM + (z*Bb + b)*Tt;
  float* wz = ws + OFF_WTAB + (z*Bb + b)*Tt;
  float wr[8]; float psum = 0.f;
  #pragma unroll
  for (int k = 0; k < 8; ++k){
    float Ea = Ez[tid + k*256] * (1.0f / (float)Dd);
    wr[k] = sqrtf(Ea + 1e-6f);
    psum += wr[k];
  }
  float tot = block_reduce_sum(psum, red, tid);
  float inv = 1.0f / (tot / (float)Tt + 1e-6f);
  #pragma unroll
  for (int k = 0; k < 8; ++k) wz[tid + k*256] = wr[k] * inv;
}

// ---------------- subspace iteration ----------------
__global__ void k_vinit(float* ws){
  int id = blockIdx.x*256 + threadIdx.x;   // Bb*Dd*Rr = 8192
  int r = id & (Rr-1); int d = (id >> 3) & (Dd-1);
  ws[OFF_V + id] = (d == r) ? 1.f : 0.f;   // d<8 identity block (d==r implies d<8)
}

__global__ void k_traces(float* ws){
  __shared__ float Vl[Dd*Rr];
  int tile = blockIdx.x, b = blockIdx.y, tid = threadIdx.x;
  for (int i = tid; i < Dd*Rr; i += 256) Vl[i] = ws[OFF_V + b*Dd*Rr + i];
  __syncthreads();
  int t = tile*256 + tid;
  float acc[Rr];
  #pragma unroll
  for (int r = 0; r < Rr; ++r) acc[r] = 0.f;
  const float* xp = ws + OFF_XPT + (b*Dd)*Tt + t;
  for (int d = 0; d < Dd; ++d){
    float xv = xp[d*Tt];
    #pragma unroll
    for (int r = 0; r < Rr; ++r) acc[r] = fmaf(xv, Vl[d*Rr + r], acc[r]);
  }
  #pragma unroll
  for (int r = 0; r < Rr; ++r) ws[OFF_YT + (b*Rr + r)*Tt + t] = acc[r];
}

__global__ __launch_bounds__(256) void k_komega(float* ws){
  __shared__ float lre[Lf], lim[Lf];
  int tid = threadIdx.x;
  int r = blockIdx.x, b = blockIdx.y, z = blockIdx.z;
  int v1 = z, v2 = z + NA;
  const float* pre1  = ws + OFF_PRE  + v1*Tt*2;
  const float* post1 = ws + OFF_POST + v1*Tt*2;
  const float* H1    = ws + OFF_H    + v1*Lf*2;
  const float* pre2  = ws + OFF_PRE  + v2*Tt*2;
  const float* post2 = ws + OFF_POST + v2*Tt*2;
  const float* H2    = ws + OFF_H    + v2*Lf*2;
  const float* twr = ws + OFF_TWR; const float* twi = ws + OFF_TWI;
  const float* ycol = ws + OFF_YT + (b*Rr + r)*Tt;
  const float* wz = ws + OFF_WTAB + (z*Bb + b)*Tt;
  // phase 1: frft(y, +alpha)
  #pragma unroll
  for (int k = 0; k < 8; ++k){
    int t = tid + k*256;
    float yv = ycol[t];
    int jb = brev12(t);
    lre[jb] = yv * pre1[t*2];
    lim[jb] = yv * pre1[t*2+1];
    int t2 = t + Tt;
    int jb2 = brev12(t2);
    lre[jb2] = 0.f; lim[jb2] = 0.f;
  }
  fft_lds(lre, lim, twr, twi, false, tid);
  mulH_and_bitrev(lre, lim, H1, tid);
  fft_lds(lre, lim, twr, twi, true, tid);
  float yar[8], yai[8];
  #pragma unroll
  for (int k = 0; k < 8; ++k){
    int t = tid + k*256;
    int j = (Tt - 1) + t;
    float cr = lre[j], ci = lim[j];
    float por = post1[t*2], poi = post1[t*2+1];
    float wv = wz[t];
    yar[k] = (por*cr - poi*ci) * wv;
    yai[k] = (por*ci + poi*cr) * wv;
  }
  __syncthreads();
  // phase 2: frft(w*Ya, -alpha)
  #pragma unroll
  for (int k = 0; k < 8; ++k){
    int t = tid + k*256;
    float p2r = pre2[t*2], p2i = pre2[t*2+1];
    int jb = brev12(t);
    lre[jb] = yar[k]*p2r - yai[k]*p2i;
    lim[jb] = yar[k]*p2i + yai[k]*p2r;
    int t2 = t + Tt;
    int jb2 = brev12(t2);
    lre[jb2] = 0.f; lim[jb2] = 0.f;
  }
  fft_lds(lre, lim, twr, twi, false, tid);
  mulH_and_bitrev(lre, lim, H2, tid);
  fft_lds(lre, lim, twr, twi, true, tid);
  float* yac = ws + OFF_YACC + (b*Rr + r)*Tt;
  #pragma unroll
  for (int k = 0; k < 8; ++k){
    int t = tid + k*256;
    int j = (Tt - 1) + t;
    float cr = lre[j], ci = lim[j];
    float por = post2[t*2], poi = post2[t*2+1];
    atomicAdd(&yac[t], por*cr - poi*ci);
  }
}

__global__ void k_zm(float* ws){
  __shared__ float red[256];
  int d = blockIdx.x, b = blockIdx.y, tid = threadIdx.x;
  const float* xcol = ws + OFF_XPT + (b*Dd + d)*Tt;
  for (int r = 0; r < Rr; ++r){
    const float* ycol = ws + OFF_YACC + (b*Rr + r)*Tt;
    float p = 0.f;
    for (int t = tid; t < Tt; t += 256) p = fmaf(xcol[t], ycol[t], p);
    float tot = block_reduce_sum(p, red, tid);
    if (tid == 0){
      float zval = tot / (float)(Tt * NA);
      ws[OFF_M + (b*Dd + d)*Rr + r] = zval + EPSf * ws[OFF_V + (b*Dd + d)*Rr + r];
    }
  }
}

__global__ void k_mgs(float* ws){
  __shared__ float q[Rr][Dd];
  __shared__ float red[256];
  int b = blockIdx.x, tid = threadIdx.x;
  float m[Rr];
  #pragma unroll
  for (int r = 0; r < Rr; ++r) m[r] = ws[OFF_M + (b*Dd + tid)*Rr + r];
  for (int r = 0; r < Rr; ++r){
    float v = m[r];
    for (int j = 0; j < r; ++j){
      float dotv = block_reduce_sum(q[j][tid] * v, red, tid);
      v = fmaf(-dotv, q[j][tid], v);
    }
    float n2 = block_reduce_sum(v * v, red, tid);
    q[r][tid] = v * rsqrtf(n2) * sqrtf(n2) / sqrtf(n2); // keep simple: v / sqrt(n2)
    q[r][tid] = v / sqrtf(n2);
    __syncthreads();
  }
  #pragma unroll
  for (int r = 0; r < Rr; ++r) ws[OFF_V + (b*Dd + tid)*Rr + r] = q[r][tid];
}

// ---------------- epilogue ----------------
__global__ void k_hbuf(float* ws){
  int bt = blockIdx.x, tid = threadIdx.x;
  int b = bt >> 11, t = bt & (Tt - 1);
  float tr[Rr];
  #pragma unroll
  for (int r = 0; r < Rr; ++r) tr[r] = ws[OFF_YT + (b*Rr + r)*Tt + t];
  const float* Vb = ws + OFF_V + (b*Dd + tid)*Rr;
  float acc = 0.f;
  #pragma unroll
  for (int r = 0; r < Rr; ++r) acc = fmaf(tr[r], Vb[r], acc);
  acc -= ws[OFF_S + bt*Dd + tid];
  if (tid == 0) acc += 1.0f;
  ws[OFF_HBUF + bt*Dd + tid] = acc;
}

__global__ void k_out(const float* x, const float* g, const float* be, float* ws, float* out){
  __shared__ float hr[Dd];
  __shared__ float red[256];
  int bt = blockIdx.x, tid = threadIdx.x;
  hr[tid] = ws[OFF_HBUF + bt*Dd + tid];
  __syncthreads();
  const float* WT = ws + OFF_WOT;
  float acc = x[bt*Dd + tid];
  for (int k = 0; k < Dd; ++k) acc = fmaf(hr[k], WT[k*Dd + tid], acc);
  float mu = block_reduce_sum(acc, red, tid) * (1.0f / (float)Dd);
  float dv = acc - mu;
  float var = block_reduce_sum(dv * dv, red, tid) * (1.0f / (float)Dd);
  out[bt*Dd + tid] = dv * rsqrtf(var + 1e-5f) * g[tid] + be[tid];
}

extern "C" void kernel_launch(void* const* d_in, const int* in_sizes, int n_in,
                              void* d_out, int out_size, void* d_ws, size_t ws_size,
                              hipStream_t stream){
  (void)in_sizes; (void)n_in; (void)out_size; (void)ws_size;
  const float* x    = (const float*)d_in[0];
  const float* Win  = (const float*)d_in[1];
  const float* Wout = (const float*)d_in[2];
  const float* bsh  = (const float*)d_in[3];
  const float* Wo   = (const float*)d_in[4];
  const float* g    = (const float*)d_in[5];
  const float* be   = (const float*)d_in[6];
  float* ws  = (float*)d_ws;
  float* out = (float*)d_out;

  hipLaunchKernelGGL(k_twiddle, dim3(1), dim3(256), 0, stream, ws);
  hipLaunchKernelGGL(k_tables, dim3(NV), dim3(256), 0, stream, ws);
  hipLaunchKernelGGL(k_hfft, dim3(NV), dim3(256), 0, stream, ws);
  hipLaunchKernelGGL(k_transpose, dim3(Dd*Dd/256), dim3(256), 0, stream, Win, Wout, Wo, ws);
  hipLaunchKernelGGL(k_u, dim3(Bb*Tt), dim3(128), 0, stream, x, ws);
  hipLaunchKernelGGL(k_sxp, dim3(Bb*Tt), dim3(256), 0, stream, x, bsh, ws);
  hipMemsetAsync(ws + OFF_ESUM, 0, (size_t)NA*Bb*Tt*sizeof(float), stream);
  hipLaunchKernelGGL(k_weights, dim3(Dd/8, Bb, NA), dim3(256), 0, stream, ws);
  hipLaunchKernelGGL(k_wnorm, dim3(Bb, NA), dim3(256), 0, stream, ws);
  hipLaunchKernelGGL(k_vinit, dim3(Bb*Dd*Rr/256), dim3(256), 0, stream, ws);
  for (int it = 0; it < 2; ++it){
    hipLaunchKernelGGL(k_traces, dim3(Tt/256, Bb), dim3(256), 0, stream, ws);
    hipMemsetAsync(ws + OFF_YACC, 0, (size_t)Bb*Rr*Tt*sizeof(float), stream);
    hipLaunchKernelGGL(k_komega, dim3(Rr, Bb, NA), dim3(256), 0, stream, ws);
    hipLaunchKernelGGL(k_zm, dim3(Dd, Bb), dim3(256), 0, stream, ws);
    hipLaunchKernelGGL(k_mgs, dim3(Bb), dim3(256), 0, stream, ws);
  }
  hipLaunchKernelGGL(k_traces, dim3(Tt/256, Bb), dim3(256), 0, stream, ws);
  hipLaunchKernelGGL(k_hbuf, dim3(Bb*Tt), dim3(256), 0, stream, ws);
  hipLaunchKernelGGL(k_out, dim3(Bb*Tt), dim3(256), 0, stream, x, g, be, ws, out);
}

// Round 3
// 583.930 us; speedup vs baseline: 2.5128x; 2.5128x over previous
//
#include <hip/hip_runtime.h>
#include <math.h>

#define Bb 4
#define Tt 2048
#define Dd 256
#define SRr 128
#define Rr 8
#define NA 8
#define NV 16
#define Lf 4096
#define LOG2L 12
#define EPSf 1e-5f
#define PI_D 3.14159265358979323846

// ---- workspace layout (floats) ----
#define OFF_TWR   0
#define OFF_TWI   (OFF_TWR + 2048)
#define OFF_TW4R  (OFF_TWI + 2048)
#define OFF_TW4I  (OFF_TW4R + 4096)
#define OFF_PRER  (OFF_TW4I + 4096)
#define OFF_PREI  (OFF_PRER + NV*Tt)
#define OFF_POSR  (OFF_PREI + NV*Tt)
#define OFF_POSI  (OFF_POSR + NV*Tt)
#define OFF_PM2   (OFF_POSI + NV*Tt)
#define OFF_H     (OFF_PM2 + NA*Tt)
#define OFF_WINT  (OFF_H + NV*Lf*2)
#define OFF_WOUTT (OFF_WINT + Dd*SRr)
#define OFF_WOT   (OFF_WOUTT + SRr*Dd)
#define OFF_WTAB  (OFF_WOT + Dd*Dd)
#define OFF_ESUM  (OFF_WTAB + NA*Bb*Tt)
#define OFF_V     (OFF_ESUM + NA*Bb*Tt)
#define OFF_M     (OFF_V + Bb*Dd*Rr)
#define OFF_YT    (OFF_M + Bb*Dd*Rr)
#define OFF_YACC  (OFF_YT + Bb*Rr*Tt)
#define OFF_S     (OFF_YACC + Bb*Rr*Tt)
#define OFF_XPT   (OFF_S + Bb*Tt*Dd)
#define OFF_HBUF  (OFF_XPT + Bb*Tt*Dd)
#define OFF_U     OFF_HBUF   /* alias: U dead before HBUF is written */

__device__ __forceinline__ int brev12(int i){ return (int)(__brev((unsigned)i) >> 20); }

__device__ float block_reduce_sum(float v, float* red, int tid){
  __syncthreads();
  red[tid] = v; __syncthreads();
  for (int s = 128; s > 0; s >>= 1){
    if (tid < s) red[tid] += red[tid + s];
    __syncthreads();
  }
  return red[0];
}

// replicate frft_time's parameter math in double (matches Python float math)
__device__ void variant_params(int v, double& s_, double& c_){
  double step = (2.99 - 0.15) / 7.0;
  int idx = v & 7;
  double alpha = (idx == 7) ? 2.99 : (0.15 + (double)idx * step);
  if (v >= 8) alpha = -alpha;
  double a = fmod(alpha + PI_D, 2.0 * PI_D);
  if (a < 0.0) a += 2.0 * PI_D;
  a -= PI_D;
  double sa = sin(a);
  s_ = ((sa >= 0.0) ? 1.0 : -1.0) / fmax(1e-7, fabs(sa));
  c_ = cos(a) / fmax(1e-7, sa);   // NOTE: reference quirk — not abs(sa)!
}

// ---------------- complex helpers / register FFT ----------------
struct cpx { float r, i; };
__device__ __forceinline__ cpx cmul(cpx a, cpx b){ return {a.r*b.r - a.i*b.i, a.r*b.i + a.i*b.r}; }
__device__ __forceinline__ cpx cmulj(cpx a, cpx b){ return {a.r*b.r + a.i*b.i, a.i*b.r - a.r*b.i}; }

__device__ __forceinline__ void fft4(cpx& a, cpx& b, cpx& c, cpx& d, float sgn){
  cpx t0{a.r+c.r, a.i+c.i}, t1{a.r-c.r, a.i-c.i};
  cpx t2{b.r+d.r, b.i+d.i}, t3{b.r-d.r, b.i-d.i};
  a = {t0.r+t2.r, t0.i+t2.i};
  c = {t0.r-t2.r, t0.i-t2.i};
  b = {t1.r - sgn*t3.i, t1.i + sgn*t3.r};   // t1 + sgn*i*t3
  d = {t1.r + sgn*t3.i, t1.i - sgn*t3.r};
}

// 16-point FFT, natural order in/out. sgn=-1: forward (exp(-i..)), +1: inverse kernel (no 1/N).
__device__ __forceinline__ void fft16(cpx x[16], float sgn){
  const float WC[10] = {1.f, 0.92387953251128674f, 0.70710678118654752f, 0.38268343236508977f,
                        0.f, -0.38268343236508977f, -0.70710678118654752f, -0.92387953251128674f,
                        -1.f, -0.92387953251128674f};
  const float WS[10] = {0.f, 0.38268343236508977f, 0.70710678118654752f, 0.92387953251128674f,
                        1.f, 0.92387953251128674f, 0.70710678118654752f, 0.38268343236508977f,
                        0.f, -0.38268343236508977f};
  #pragma unroll
  for (int j0 = 0; j0 < 4; ++j0)
    fft4(x[j0], x[j0+4], x[j0+8], x[j0+12], sgn);
  // x[j0 + 4*p0] = A[j0][p0]; twiddle by w16^{j0*p0}
  #pragma unroll
  for (int j0 = 1; j0 < 4; ++j0){
    #pragma unroll
    for (int p0 = 1; p0 < 4; ++p0){
      int m = j0*p0;
      cpx w{WC[m], sgn*WS[m]};
      x[j0 + 4*p0] = cmul(x[j0 + 4*p0], w);
    }
  }
  #pragma unroll
  for (int p0 = 0; p0 < 4; ++p0)
    fft4(x[4*p0+0], x[4*p0+1], x[4*p0+2], x[4*p0+3], sgn);
  // X[4*p1+p0] currently at x[4*p0+p1] -> transpose register indices
  cpx t;
  t=x[1];  x[1]=x[4];   x[4]=t;
  t=x[2];  x[2]=x[8];   x[8]=t;
  t=x[3];  x[3]=x[12];  x[12]=t;
  t=x[6];  x[6]=x[9];   x[9]=t;
  t=x[7];  x[7]=x[13];  x[13]=t;
  t=x[11]; x[11]=x[14]; x[14]=t;
}

// 4096-pt FFT, four-step 16x16x16. Input: thread t holds x[j*256+t], j=0..15.
// OUTPUT MAPPING (derived, round-2 fix): thread tid=(hi,lo) register r holds
//   X[k] with k = hi + 16*lo + 256*r   (self-sorting, natural order across the block).
// twA[p]=w4096^{tid*p}, twB[q]=w4096^{16*lo*q} (forward convention); inverse uses conj.
__device__ __forceinline__ void fft4096(cpx x[16], float* sre, float* sim,
                                        const cpx twA[16], const cpx twB[16],
                                        int tid, float sgn){
  int hi = tid >> 4, lo = tid & 15;
  fft16(x, sgn);
  #pragma unroll
  for (int p = 1; p < 16; ++p) x[p] = (sgn < 0.f) ? cmul(x[p], twA[p]) : cmulj(x[p], twA[p]);
  __syncthreads();                       // prior reads done before overwrite
  #pragma unroll
  for (int p = 0; p < 16; ++p){ int a = p*272 + 17*hi + lo; sre[a] = x[p].r; sim[a] = x[p].i; }
  __syncthreads();
  #pragma unroll
  for (int u = 0; u < 16; ++u){ int a = hi*272 + 17*u + lo; x[u] = {sre[a], sim[a]}; }
  fft16(x, sgn);
  #pragma unroll
  for (int q = 1; q < 16; ++q) x[q] = (sgn < 0.f) ? cmul(x[q], twB[q]) : cmulj(x[q], twB[q]);
  __syncthreads();
  #pragma unroll
  for (int q = 0; q < 16; ++q){ int a = hi*272 + 17*q + lo; sre[a] = x[q].r; sim[a] = x[q].i; }
  __syncthreads();
  #pragma unroll
  for (int v = 0; v < 16; ++v){ int a = hi*272 + 17*lo + v; x[v] = {sre[a], sim[a]}; }
  fft16(x, sgn);
}

// legacy radix-2 LDS FFT (k_hfft only; runs 16 blocks once per launch)
__device__ void fft_lds(float* re, float* im, const float* twr, const float* twi,
                        bool inv, int tid){
  for (int st = 1; st <= LOG2L; ++st){
    __syncthreads();
    int half = 1 << (st - 1);
    int stepT = Lf >> st;
    for (int j = tid; j < Lf/2; j += 256){
      int pos = j & (half - 1);
      int i0 = ((j >> (st - 1)) << st) + pos;
      int i1 = i0 + half;
      float wr = twr[pos * stepT];
      float wi = twi[pos * stepT];
      if (inv) wi = -wi;
      float br = re[i1], bi = im[i1];
      float tr = br * wr - bi * wi;
      float ti = br * wi + bi * wr;
      float ar = re[i0], ai = im[i0];
      re[i0] = ar + tr; im[i0] = ai + ti;
      re[i1] = ar - tr; im[i1] = ai - ti;
    }
  }
  __syncthreads();
}

// ---------------- setup kernels ----------------
__global__ void k_twiddle(float* ws){
  for (int k = threadIdx.x; k < 2048; k += 256){
    double ang = -2.0 * PI_D * (double)k / (double)Lf;
    ws[OFF_TWR + k] = (float)cos(ang);
    ws[OFF_TWI + k] = (float)sin(ang);
  }
  for (int k = threadIdx.x; k < 4096; k += 256){
    double ang = -2.0 * PI_D * (double)k / (double)Lf;
    ws[OFF_TW4R + k] = (float)cos(ang);
    ws[OFF_TW4I + k] = (float)sin(ang);
  }
}

__global__ void k_tables(float* ws){
  int v = blockIdx.x;
  double s_, c_;
  variant_params(v, s_, c_);
  double dt = 2.0 / (double)(Tt - 1);
  double cf = (double)(float)c_;
  double rmag = sqrt(1.0 + cf * cf);
  double pr = sqrt((rmag + 1.0) * 0.5);
  double pim = ((cf >= 0.0) ? -1.0 : 1.0) * sqrt(fmax(0.0, (rmag - 1.0) * 0.5));
  double cps = PI_D * (c_ + s_);
  double sc = dt / (double)Lf;   // fold dt and 1/L (ifft scale) into post
  for (int k = threadIdx.x; k < Tt; k += 256){
    double t = (k == Tt - 1) ? 1.0 : ((double)k * dt - 1.0);
    double th = cps * (t * t);
    double cr = cos(th), ci = sin(th);
    ws[OFF_PRER + v*Tt + k] = (float)cr;
    ws[OFF_PREI + v*Tt + k] = (float)ci;
    float por = (float)((pr*cr - pim*ci) * sc);
    float poi = (float)((pr*ci + pim*cr) * sc);
    ws[OFF_POSR + v*Tt + k] = por;
    ws[OFF_POSI + v*Tt + k] = poi;
    if (v < NA) ws[OFF_PM2 + v*Tt + k] = por*por + poi*poi;
  }
}

__global__ __launch_bounds__(256) void k_hfft(float* ws){
  __shared__ float lre[Lf], lim[Lf];
  int v = blockIdx.x, tid = threadIdx.x;
  double s_, c_;
  variant_params(v, s_, c_);
  double dt = 2.0 / (double)(Tt - 1);
  for (int i = tid; i < Lf; i += 256){ lre[i] = 0.f; lim[i] = 0.f; }
  __syncthreads();
  double ns = -(PI_D * s_);
  for (int mm = tid; mm < 2*Tt - 1; mm += 256){
    int m = mm - (Tt - 1);
    double md = (double)m * dt;
    double th = ns * (md * md);
    int j = (m + Lf) & (Lf - 1);
    int jb = brev12(j);
    lre[jb] = (float)cos(th);
    lim[jb] = (float)sin(th);
  }
  fft_lds(lre, lim, ws + OFF_TWR, ws + OFF_TWI, false, tid);
  for (int i = tid; i < Lf; i += 256){
    ws[OFF_H + (v*Lf + i)*2 + 0] = lre[i];
    ws[OFF_H + (v*Lf + i)*2 + 1] = lim[i];
  }
}

__global__ void k_transpose(const float* Win, const float* Wout, const float* Wo, float* ws){
  int id = blockIdx.x * 256 + threadIdx.x;   // 65536 threads
  { int d = id & (Dd-1); int k = id >> 8; ws[OFF_WOT + id] = Wo[d*Dd + k]; }
  if (id < Dd*SRr){
    int c = id & (SRr-1); int k = id >> 7;            // WinT[k*SR+c] = Win[c*D+k]
    ws[OFF_WINT + id] = Win[c*Dd + k];
    int d2 = id & (Dd-1); int k2 = id >> 8;           // WoutT[k*D+d] = Wout[d*SR+k]
    ws[OFF_WOUTT + id] = Wout[d2*SRr + k2];
  }
}

// ---------------- shift + xprime ----------------
__global__ void k_u(const float* x, float* ws){
  __shared__ float xr[Dd];
  int bt = blockIdx.x, tid = threadIdx.x;  // 128 threads
  xr[tid] = x[bt*Dd + tid];
  xr[tid + 128] = x[bt*Dd + tid + 128];
  __syncthreads();
  const float* WT = ws + OFF_WINT;
  float acc = 0.f;
  for (int k = 0; k < Dd; ++k) acc = fmaf(xr[k], WT[k*SRr + tid], acc);
  float u = 0.5f * acc * (1.0f + erff(acc * 0.70710678118654752f));
  ws[OFF_U + bt*SRr + tid] = u;
}

__global__ void k_sxp(const float* x, const float* bsh, float* ws){
  __shared__ float ur[SRr];
  int bt = blockIdx.x, tid = threadIdx.x;  // 256 threads
  if (tid < SRr) ur[tid] = ws[OFF_U + bt*SRr + tid];
  __syncthreads();
  const float* WT = ws + OFF_WOUTT;
  float acc = bsh[tid];
  for (int k = 0; k < SRr; ++k) acc = fmaf(ur[k], WT[k*Dd + tid], acc);
  float xv = x[bt*Dd + tid];
  float anc = (tid == 0) ? 1.0f : 0.0f;
  float xp = xv - anc + acc;
  ws[OFF_S + bt*Dd + tid] = acc;
  int b = bt >> 11, t = bt & (Tt - 1);
  ws[OFF_XPT + (b*Dd + tid)*Tt + t] = xp;
}

// ---------------- FrFT energy weights (register FFT) ----------------
__global__ __launch_bounds__(256) void k_weights(float* ws){
  __shared__ float sre[16*272], sim[16*272];
  int tid = threadIdx.x;
  int chunk = blockIdx.x, b = blockIdx.y, z = blockIdx.z;
  int hi = tid >> 4, lo = tid & 15;
  int base = hi + 16*lo;                 // k = base + 256*r (true four-step mapping)
  const float* tw4r = ws + OFF_TW4R; const float* tw4i = ws + OFF_TW4I;
  cpx twA[16], twB[16];
  #pragma unroll
  for (int p = 0; p < 16; ++p){
    int iA = tid * p;      twA[p] = {tw4r[iA], tw4i[iA]};
    int iB = 16 * lo * p;  twB[p] = {tw4r[iB], tw4i[iB]};
  }
  const float* prer = ws + OFF_PRER + z*Tt;
  const float* prei = ws + OFF_PREI + z*Tt;
  const float* pm2  = ws + OFF_PM2  + z*Tt;
  const float* Hv   = ws + OFF_H    + z*Lf*2;
  float e[16];
  #pragma unroll
  for (int r = 0; r < 16; ++r) e[r] = 0.f;
  for (int cc = 0; cc < 8; ++cc){
    int c = chunk*8 + cc;
    const float* xcol = ws + OFF_XPT + (b*Dd + c)*Tt;
    cpx x[16];
    #pragma unroll
    for (int j = 0; j < 16; ++j){
      if (j < 8){
        int t = j*256 + tid;
        float xv = xcol[t];
        x[j] = {xv * prer[t], xv * prei[t]};
      } else x[j] = {0.f, 0.f};
    }
    fft4096(x, sre, sim, twA, twB, tid, -1.f);
    #pragma unroll
    for (int r = 0; r < 16; ++r){
      int k = base + 256*r;
      cpx h{Hv[2*k], Hv[2*k+1]};
      x[r] = cmul(x[r], h);
    }
    // redistribute spectrum to j-major layout for inverse pass:
    // reg r holds G[k], k = base+256r -> plane k>>8 = r, position k&255 = base = 16*lo+hi
    __syncthreads();
    #pragma unroll
    for (int r = 0; r < 16; ++r){ int a = r*272 + 17*lo + hi; sre[a] = x[r].r; sim[a] = x[r].i; }
    __syncthreads();
    #pragma unroll
    for (int j = 0; j < 16; ++j){ int a = j*272 + 17*hi + lo; x[j] = {sre[a], sim[a]}; }
    fft4096(x, sre, sim, twA, twB, tid, +1.f);
    #pragma unroll
    for (int r = 0; r < 16; ++r){
      int k = base + 256*r;
      if (k >= 2047 && k < 4095){
        int t = k - 2047;
        e[r] += pm2[t] * (x[r].r*x[r].r + x[r].i*x[r].i);
      }
    }
  }
  float* Ez = ws + OFF_ESUM + (z*Bb + b)*Tt;
  #pragma unroll
  for (int r = 0; r < 16; ++r){
    int k = base + 256*r;
    if (k >= 2047 && k < 4095) atomicAdd(&Ez[k - 2047], e[r]);
  }
}

__global__ void k_wnorm(float* ws){
  __shared__ float red[256];
  int b = blockIdx.x, z = blockIdx.y, tid = threadIdx.x;
  const float* Ez = ws + OFF_ESUM + (z*Bb + b)*Tt;
  float* wz = ws + OFF_WTAB + (z*Bb + b)*Tt;
  float wr[8]; float psum = 0.f;
  #pragma unroll
  for (int k = 0; k < 8; ++k){
    float Ea = Ez[tid + k*256] * (1.0f / (float)Dd);
    wr[k] = sqrtf(Ea + 1e-6f);
    psum += wr[k];
  }
  float tot = block_reduce_sum(psum, red, tid);
  float inv = 1.0f / (tot / (float)Tt + 1e-6f);
  #pragma unroll
  for (int k = 0; k < 8; ++k) wz[tid + k*256] = wr[k] * inv;
}

// ---------------- subspace iteration ----------------
__global__ void k_vinit(float* ws){
  int id = blockIdx.x*256 + threadIdx.x;   // Bb*Dd*Rr = 8192
  int r = id & (Rr-1); int d = (id >> 3) & (Dd-1);
  ws[OFF_V + id] = (d == r) ? 1.f : 0.f;
}

__global__ void k_traces(float* ws){
  __shared__ float Vl[Dd*Rr];
  int tile = blockIdx.x, b = blockIdx.y, tid = threadIdx.x;
  for (int i = tid; i < Dd*Rr; i += 256) Vl[i] = ws[OFF_V + b*Dd*Rr + i];
  __syncthreads();
  int t = tile*256 + tid;
  float acc[Rr];
  #pragma unroll
  for (int r = 0; r < Rr; ++r) acc[r] = 0.f;
  const float* xp = ws + OFF_XPT + (b*Dd)*Tt + t;
  for (int d = 0; d < Dd; ++d){
    float xv = xp[d*Tt];
    #pragma unroll
    for (int r = 0; r < Rr; ++r) acc[r] = fmaf(xv, Vl[d*Rr + r], acc[r]);
  }
  #pragma unroll
  for (int r = 0; r < Rr; ++r) ws[OFF_YT + (b*Rr + r)*Tt + t] = acc[r];
}

__global__ __launch_bounds__(256) void k_komega(float* ws){
  __shared__ float sre[16*272], sim[16*272];
  int tid = threadIdx.x;
  int rr = blockIdx.x, b = blockIdx.y, z = blockIdx.z;
  int hi = tid >> 4, lo = tid & 15;
  int base = hi + 16*lo;                 // k = base + 256*r
  int v1 = z, v2 = z + NA;
  const float* tw4r = ws + OFF_TW4R; const float* tw4i = ws + OFF_TW4I;
  cpx twA[16], twB[16];
  #pragma unroll
  for (int p = 0; p < 16; ++p){
    int iA = tid * p;      twA[p] = {tw4r[iA], tw4i[iA]};
    int iB = 16 * lo * p;  twB[p] = {tw4r[iB], tw4i[iB]};
  }
  const float* prer1 = ws + OFF_PRER + v1*Tt; const float* prei1 = ws + OFF_PREI + v1*Tt;
  const float* posr1 = ws + OFF_POSR + v1*Tt; const float* posi1 = ws + OFF_POSI + v1*Tt;
  const float* prer2 = ws + OFF_PRER + v2*Tt; const float* prei2 = ws + OFF_PREI + v2*Tt;
  const float* posr2 = ws + OFF_POSR + v2*Tt; const float* posi2 = ws + OFF_POSI + v2*Tt;
  const float* H1 = ws + OFF_H + v1*Lf*2;
  const float* H2 = ws + OFF_H + v2*Lf*2;
  const float* wz = ws + OFF_WTAB + (z*Bb + b)*Tt;
  const float* ycol = ws + OFF_YT + (b*Rr + rr)*Tt;
  float* yac = ws + OFF_YACC + (b*Rr + rr)*Tt;
  cpx x[16];
  // ---- phase 1: frft(y, +alpha) ----
  #pragma unroll
  for (int j = 0; j < 16; ++j){
    if (j < 8){
      int t = j*256 + tid;
      float yv = ycol[t];
      x[j] = {yv * prer1[t], yv * prei1[t]};
    } else x[j] = {0.f, 0.f};
  }
  fft4096(x, sre, sim, twA, twB, tid, -1.f);
  #pragma unroll
  for (int r = 0; r < 16; ++r){ int k = base + 256*r; cpx h{H1[2*k], H1[2*k+1]}; x[r] = cmul(x[r], h); }
  __syncthreads();
  #pragma unroll
  for (int r = 0; r < 16; ++r){ int a = r*272 + 17*lo + hi; sre[a] = x[r].r; sim[a] = x[r].i; }
  __syncthreads();
  #pragma unroll
  for (int j = 0; j < 16; ++j){ int a = j*272 + 17*hi + lo; x[j] = {sre[a], sim[a]}; }
  fft4096(x, sre, sim, twA, twB, tid, +1.f);
  // ---- Ya*post1*w*pre2 -> redistribute to j-major (t-digit) layout ----
  __syncthreads();
  #pragma unroll
  for (int r = 0; r < 16; ++r){
    int k = base + 256*r;
    if (k >= 2047 && k < 4095){
      int t = k - 2047;
      float cr = x[r].r, ci = x[r].i;
      float wv = wz[t];
      float yar = (posr1[t]*cr - posi1[t]*ci) * wv;
      float yai = (posr1[t]*ci + posi1[t]*cr) * wv;
      float gr = yar*prer2[t] - yai*prei2[t];
      float gi = yar*prei2[t] + yai*prer2[t];
      int a = (t >> 8)*272 + 17*((t >> 4) & 15) + (t & 15);
      sre[a] = gr; sim[a] = gi;
    }
  }
  __syncthreads();
  // ---- phase 2: frft(w*Ya, -alpha) ----
  #pragma unroll
  for (int j = 0; j < 16; ++j){
    if (j < 8){ int a = j*272 + 17*hi + lo; x[j] = {sre[a], sim[a]}; }
    else x[j] = {0.f, 0.f};
  }
  fft4096(x, sre, sim, twA, twB, tid, -1.f);
  #pragma unroll
  for (int r = 0; r < 16; ++r){ int k = base + 256*r; cpx h{H2[2*k], H2[2*k+1]}; x[r] = cmul(x[r], h); }
  __syncthreads();
  #pragma unroll
  for (int r = 0; r < 16; ++r){ int a = r*272 + 17*lo + hi; sre[a] = x[r].r; sim[a] = x[r].i; }
  __syncthreads();
  #pragma unroll
  for (int j = 0; j < 16; ++j){ int a = j*272 + 17*hi + lo; x[j] = {sre[a], sim[a]}; }
  fft4096(x, sre, sim, twA, twB, tid, +1.f);
  #pragma unroll
  for (int r = 0; r < 16; ++r){
    int k = base + 256*r;
    if (k >= 2047 && k < 4095){
      int t = k - 2047;
      atomicAdd(&yac[t], posr2[t]*x[r].r - posi2[t]*x[r].i);
    }
  }
}

__global__ void k_zm(float* ws){
  __shared__ float red[256];
  int d = blockIdx.x, b = blockIdx.y, tid = threadIdx.x;
  const float* xcol = ws + OFF_XPT + (b*Dd + d)*Tt;
  for (int r = 0; r < Rr; ++r){
    const float* ycol = ws + OFF_YACC + (b*Rr + r)*Tt;
    float p = 0.f;
    for (int t = tid; t < Tt; t += 256) p = fmaf(xcol[t], ycol[t], p);
    float tot = block_reduce_sum(p, red, tid);
    if (tid == 0){
      float zval = tot / (float)(Tt * NA);
      ws[OFF_M + (b*Dd + d)*Rr + r] = zval + EPSf * ws[OFF_V + (b*Dd + d)*Rr + r];
    }
  }
}

__global__ void k_mgs(float* ws){
  __shared__ float q[Rr][Dd];
  __shared__ float red[256];
  int b = blockIdx.x, tid = threadIdx.x;
  float m[Rr];
  #pragma unroll
  for (int r = 0; r < Rr; ++r) m[r] = ws[OFF_M + (b*Dd + tid)*Rr + r];
  for (int r = 0; r < Rr; ++r){
    float v = m[r];
    for (int j = 0; j < r; ++j){
      float dotv = block_reduce_sum(q[j][tid] * v, red, tid);
      v = fmaf(-dotv, q[j][tid], v);
    }
    float n2 = block_reduce_sum(v * v, red, tid);
    q[r][tid] = v / sqrtf(n2);
    __syncthreads();
  }
  #pragma unroll
  for (int r = 0; r < Rr; ++r) ws[OFF_V + (b*Dd + tid)*Rr + r] = q[r][tid];
}

// ---------------- epilogue ----------------
__global__ void k_hbuf(float* ws){
  int bt = blockIdx.x, tid = threadIdx.x;
  int b = bt >> 11, t = bt & (Tt - 1);
  float tr[Rr];
  #pragma unroll
  for (int r = 0; r < Rr; ++r) tr[r] = ws[OFF_YT + (b*Rr + r)*Tt + t];
  const float* Vb = ws + OFF_V + (b*Dd + tid)*Rr;
  float acc = 0.f;
  #pragma unroll
  for (int r = 0; r < Rr; ++r) acc = fmaf(tr[r], Vb[r], acc);
  acc -= ws[OFF_S + bt*Dd + tid];
  if (tid == 0) acc += 1.0f;
  ws[OFF_HBUF + bt*Dd + tid] = acc;
}

__global__ void k_out(const float* x, const float* g, const float* be, float* ws, float* out){
  __shared__ float hr[Dd];
  __shared__ float red[256];
  int bt = blockIdx.x, tid = threadIdx.x;
  hr[tid] = ws[OFF_HBUF + bt*Dd + tid];
  __syncthreads();
  const float* WT = ws + OFF_WOT;
  float acc = x[bt*Dd + tid];
  for (int k = 0; k < Dd; ++k) acc = fmaf(hr[k], WT[k*Dd + tid], acc);
  float mu = block_reduce_sum(acc, red, tid) * (1.0f / (float)Dd);
  float dv = acc - mu;
  float var = block_reduce_sum(dv * dv, red, tid) * (1.0f / (float)Dd);
  out[bt*Dd + tid] = dv * rsqrtf(var + 1e-5f) * g[tid] + be[tid];
}

extern "C" void kernel_launch(void* const* d_in, const int* in_sizes, int n_in,
                              void* d_out, int out_size, void* d_ws, size_t ws_size,
                              hipStream_t stream){
  (void)in_sizes; (void)n_in; (void)out_size; (void)ws_size;
  const float* x    = (const float*)d_in[0];
  const float* Win  = (const float*)d_in[1];
  const float* Wout = (const float*)d_in[2];
  const float* bsh  = (const float*)d_in[3];
  const float* Wo   = (const float*)d_in[4];
  const float* g    = (const float*)d_in[5];
  const float* be   = (const float*)d_in[6];
  float* ws  = (float*)d_ws;
  float* out = (float*)d_out;

  hipLaunchKernelGGL(k_twiddle, dim3(1), dim3(256), 0, stream, ws);
  hipLaunchKernelGGL(k_tables, dim3(NV), dim3(256), 0, stream, ws);
  hipLaunchKernelGGL(k_hfft, dim3(NV), dim3(256), 0, stream, ws);
  hipLaunchKernelGGL(k_transpose, dim3(Dd*Dd/256), dim3(256), 0, stream, Win, Wout, Wo, ws);
  hipLaunchKernelGGL(k_u, dim3(Bb*Tt), dim3(128), 0, stream, x, ws);
  hipLaunchKernelGGL(k_sxp, dim3(Bb*Tt), dim3(256), 0, stream, x, bsh, ws);
  hipMemsetAsync(ws + OFF_ESUM, 0, (size_t)NA*Bb*Tt*sizeof(float), stream);
  hipLaunchKernelGGL(k_weights, dim3(Dd/8, Bb, NA), dim3(256), 0, stream, ws);
  hipLaunchKernelGGL(k_wnorm, dim3(Bb, NA), dim3(256), 0, stream, ws);
  hipLaunchKernelGGL(k_vinit, dim3(Bb*Dd*Rr/256), dim3(256), 0, stream, ws);
  for (int it = 0; it < 2; ++it){
    hipLaunchKernelGGL(k_traces, dim3(Tt/256, Bb), dim3(256), 0, stream, ws);
    hipMemsetAsync(ws + OFF_YACC, 0, (size_t)Bb*Rr*Tt*sizeof(float), stream);
    hipLaunchKernelGGL(k_komega, dim3(Rr, Bb, NA), dim3(256), 0, stream, ws);
    hipLaunchKernelGGL(k_zm, dim3(Dd, Bb), dim3(256), 0, stream, ws);
    hipLaunchKernelGGL(k_mgs, dim3(Bb), dim3(256), 0, stream, ws);
  }
  hipLaunchKernelGGL(k_traces, dim3(Tt/256, Bb), dim3(256), 0, stream, ws);
  hipLaunchKernelGGL(k_hbuf, dim3(Bb*Tt), dim3(256), 0, stream, ws);
  hipLaunchKernelGGL(k_out, dim3(Bb*Tt), dim3(256), 0, stream, x, g, be, ws, out);
}

// Round 4
// 487.625 us; speedup vs baseline: 3.0091x; 1.1975x over previous
//
#include <hip/hip_runtime.h>
#include <math.h>

#define Bb 4
#define Tt 2048
#define Dd 256
#define SRr 128
#define Rr 8
#define NA 8
#define NV 16
#define Lf 4096
#define EPSf 1e-5f
#define PI_D 3.14159265358979323846

// ---- workspace layout (floats) ----
#define OFF_TW4R  0
#define OFF_TW4I  (OFF_TW4R + 4096)
#define OFF_PRER  (OFF_TW4I + 4096)
#define OFF_PREI  (OFF_PRER + NV*Tt)
#define OFF_POSR  (OFF_PREI + NV*Tt)
#define OFF_POSI  (OFF_POSR + NV*Tt)
#define OFF_PM2   (OFF_POSI + NV*Tt)
#define OFF_H     (OFF_PM2 + NA*Tt)
#define OFF_WINT  (OFF_H + NV*Lf*2)
#define OFF_WOUTT (OFF_WINT + Dd*SRr)
#define OFF_WOT   (OFF_WOUTT + SRr*Dd)
#define OFF_WTAB  (OFF_WOT + Dd*Dd)
#define OFF_ESUM  (OFF_WTAB + NA*Bb*Tt)
#define OFF_V     (OFF_ESUM + NA*Bb*Tt)
#define OFF_M     (OFF_V + Bb*Dd*Rr)
#define OFF_YT    (OFF_M + Bb*Dd*Rr)
#define OFF_YACC  (OFF_YT + Bb*Rr*Tt)
#define OFF_S     (OFF_YACC + Bb*Rr*Tt)
#define OFF_XPT   (OFF_S + Bb*Tt*Dd)

// shuffle-based block reduce: 2 syncs instead of ~18
__device__ __forceinline__ float block_reduce_sum(float v, float* red, int tid){
  #pragma unroll
  for (int o = 32; o > 0; o >>= 1) v += __shfl_xor(v, o, 64);
  __syncthreads();
  if ((tid & 63) == 0) red[tid >> 6] = v;
  __syncthreads();
  return red[0] + red[1] + red[2] + red[3];
}

// replicate frft_time's parameter math in double (matches Python float math)
__device__ void variant_params(int v, double& s_, double& c_){
  double step = (2.99 - 0.15) / 7.0;
  int idx = v & 7;
  double alpha = (idx == 7) ? 2.99 : (0.15 + (double)idx * step);
  if (v >= 8) alpha = -alpha;
  double a = fmod(alpha + PI_D, 2.0 * PI_D);
  if (a < 0.0) a += 2.0 * PI_D;
  a -= PI_D;
  double sa = sin(a);
  s_ = ((sa >= 0.0) ? 1.0 : -1.0) / fmax(1e-7, fabs(sa));
  c_ = cos(a) / fmax(1e-7, sa);   // NOTE: reference quirk — not abs(sa)!
}

// ---------------- complex helpers / register FFT ----------------
struct cpx { float r, i; };
__device__ __forceinline__ cpx cmul(cpx a, cpx b){ return {a.r*b.r - a.i*b.i, a.r*b.i + a.i*b.r}; }
__device__ __forceinline__ cpx cmulj(cpx a, cpx b){ return {a.r*b.r + a.i*b.i, a.i*b.r - a.r*b.i}; }

__device__ __forceinline__ void fft4(cpx& a, cpx& b, cpx& c, cpx& d, float sgn){
  cpx t0{a.r+c.r, a.i+c.i}, t1{a.r-c.r, a.i-c.i};
  cpx t2{b.r+d.r, b.i+d.i}, t3{b.r-d.r, b.i-d.i};
  a = {t0.r+t2.r, t0.i+t2.i};
  c = {t0.r-t2.r, t0.i-t2.i};
  b = {t1.r - sgn*t3.i, t1.i + sgn*t3.r};   // t1 + sgn*i*t3
  d = {t1.r + sgn*t3.i, t1.i - sgn*t3.r};
}

__device__ __forceinline__ void fft16(cpx x[16], float sgn){
  const float WC[10] = {1.f, 0.92387953251128674f, 0.70710678118654752f, 0.38268343236508977f,
                        0.f, -0.38268343236508977f, -0.70710678118654752f, -0.92387953251128674f,
                        -1.f, -0.92387953251128674f};
  const float WS[10] = {0.f, 0.38268343236508977f, 0.70710678118654752f, 0.92387953251128674f,
                        1.f, 0.92387953251128674f, 0.70710678118654752f, 0.38268343236508977f,
                        0.f, -0.38268343236508977f};
  #pragma unroll
  for (int j0 = 0; j0 < 4; ++j0)
    fft4(x[j0], x[j0+4], x[j0+8], x[j0+12], sgn);
  #pragma unroll
  for (int j0 = 1; j0 < 4; ++j0){
    #pragma unroll
    for (int p0 = 1; p0 < 4; ++p0){
      int m = j0*p0;
      cpx w{WC[m], sgn*WS[m]};
      x[j0 + 4*p0] = cmul(x[j0 + 4*p0], w);
    }
  }
  #pragma unroll
  for (int p0 = 0; p0 < 4; ++p0)
    fft4(x[4*p0+0], x[4*p0+1], x[4*p0+2], x[4*p0+3], sgn);
  cpx t;
  t=x[1];  x[1]=x[4];   x[4]=t;
  t=x[2];  x[2]=x[8];   x[8]=t;
  t=x[3];  x[3]=x[12];  x[12]=t;
  t=x[6];  x[6]=x[9];   x[9]=t;
  t=x[7];  x[7]=x[13];  x[13]=t;
  t=x[11]; x[11]=x[14]; x[14]=t;
}

// 4096-pt four-step FFT. Input: thread tid holds x[j*256+tid].
// Output: thread tid=(hi,lo) reg r holds X[k], k = hi + 16*lo + 256*r.
__device__ __forceinline__ void fft4096(cpx x[16], float* sre, float* sim,
                                        const cpx twA[16], const cpx twB[16],
                                        int tid, float sgn){
  int hi = tid >> 4, lo = tid & 15;
  fft16(x, sgn);
  #pragma unroll
  for (int p = 1; p < 16; ++p) x[p] = (sgn < 0.f) ? cmul(x[p], twA[p]) : cmulj(x[p], twA[p]);
  __syncthreads();
  #pragma unroll
  for (int p = 0; p < 16; ++p){ int a = p*272 + 17*hi + lo; sre[a] = x[p].r; sim[a] = x[p].i; }
  __syncthreads();
  #pragma unroll
  for (int u = 0; u < 16; ++u){ int a = hi*272 + 17*u + lo; x[u] = {sre[a], sim[a]}; }
  fft16(x, sgn);
  #pragma unroll
  for (int q = 1; q < 16; ++q) x[q] = (sgn < 0.f) ? cmul(x[q], twB[q]) : cmulj(x[q], twB[q]);
  __syncthreads();
  #pragma unroll
  for (int q = 0; q < 16; ++q){ int a = hi*272 + 17*q + lo; sre[a] = x[q].r; sim[a] = x[q].i; }
  __syncthreads();
  #pragma unroll
  for (int v = 0; v < 16; ++v){ int a = hi*272 + 17*lo + v; x[v] = {sre[a], sim[a]}; }
  fft16(x, sgn);
}

// ---------------- setup kernels ----------------
__global__ void k_twiddle(float* ws){
  int id = blockIdx.x*256 + threadIdx.x;
  for (int k = id; k < 4096; k += 4096){
    double ang = -2.0 * PI_D * (double)k / (double)Lf;
    ws[OFF_TW4R + k] = (float)cos(ang);
    ws[OFF_TW4I + k] = (float)sin(ang);
  }
}

__global__ void k_tables(float* ws){
  int v = blockIdx.x;
  double s_, c_;
  variant_params(v, s_, c_);
  double dt = 2.0 / (double)(Tt - 1);
  double cf = (double)(float)c_;
  double rmag = sqrt(1.0 + cf * cf);
  double pr = sqrt((rmag + 1.0) * 0.5);
  double pim = ((cf >= 0.0) ? -1.0 : 1.0) * sqrt(fmax(0.0, (rmag - 1.0) * 0.5));
  double cps = PI_D * (c_ + s_);
  double sc = dt / (double)Lf;
  for (int k = threadIdx.x; k < Tt; k += 256){
    double t = (k == Tt - 1) ? 1.0 : ((double)k * dt - 1.0);
    double th = cps * (t * t);
    double cr = cos(th), ci = sin(th);
    ws[OFF_PRER + v*Tt + k] = (float)cr;
    ws[OFF_PREI + v*Tt + k] = (float)ci;
    float por = (float)((pr*cr - pim*ci) * sc);
    float poi = (float)((pr*ci + pim*cr) * sc);
    ws[OFF_POSR + v*Tt + k] = por;
    ws[OFF_POSI + v*Tt + k] = poi;
    if (v < NA) ws[OFF_PM2 + v*Tt + k] = por*por + poi*poi;
  }
}

// H spectrum via register four-step FFT (replaces radix-2 path)
__global__ __launch_bounds__(256) void k_hfft(float* ws){
  __shared__ float sre[16*272], sim[16*272];
  int v = blockIdx.x, tid = threadIdx.x;
  int hi = tid >> 4, lo = tid & 15;
  int base = hi + 16*lo;
  double s_, c_;
  variant_params(v, s_, c_);
  double dt = 2.0 / (double)(Tt - 1);
  double ns = -(PI_D * s_);
  const float* tw4r = ws + OFF_TW4R; const float* tw4i = ws + OFF_TW4I;
  cpx twA[16], twB[16];
  #pragma unroll
  for (int p = 0; p < 16; ++p){
    int iA = tid * p;      twA[p] = {tw4r[iA], tw4i[iA]};
    int iB = 16 * lo * p;  twB[p] = {tw4r[iB], tw4i[iB]};
  }
  cpx x[16];
  #pragma unroll
  for (int j = 0; j < 16; ++j){
    int n = j*256 + tid;
    if (n == 2048){ x[j] = {0.f, 0.f}; continue; }
    int m = (n <= 2047) ? n : (n - 4096);
    double md = (double)m * dt;
    double th = ns * (md * md);
    x[j] = {(float)cos(th), (float)sin(th)};
  }
  fft4096(x, sre, sim, twA, twB, tid, -1.f);
  #pragma unroll
  for (int r = 0; r < 16; ++r){
    int k = base + 256*r;
    ws[OFF_H + (v*Lf + k)*2 + 0] = x[r].r;
    ws[OFF_H + (v*Lf + k)*2 + 1] = x[r].i;
  }
}

__global__ void k_transpose(const float* Win, const float* Wout, const float* Wo, float* ws){
  int id = blockIdx.x * 256 + threadIdx.x;   // 65536 threads
  { int d = id & (Dd-1); int k = id >> 8; ws[OFF_WOT + id] = Wo[d*Dd + k]; }
  if (id < Dd*SRr){
    int c = id & (SRr-1); int k = id >> 7;
    ws[OFF_WINT + id] = Win[c*Dd + k];
    int d2 = id & (Dd-1); int k2 = id >> 8;
    ws[OFF_WOUTT + id] = Wout[d2*SRr + k2];
  }
}

// ---------------- fused shift: u = gelu(x@WinT), s = u@WoutT + b, xprime ----------------
__global__ __launch_bounds__(256) void k_shift(const float* x, const float* bsh, float* ws){
  __shared__ float xs[16][Dd];
  __shared__ float us[16][SRr];
  int tid = threadIdx.x;
  int g0 = blockIdx.x * 16;          // 16 rows per block
  int b = g0 >> 11, t0 = g0 & (Tt - 1);
  #pragma unroll
  for (int row = 0; row < 16; ++row)
    xs[row][tid] = x[(g0 + row)*Dd + tid];
  __syncthreads();
  // phase 1: u[16][128]
  int col = tid & 127, rowgrp = tid >> 7;   // rowgrp*8 .. +7
  {
    float acc[8];
    #pragma unroll
    for (int rr = 0; rr < 8; ++rr) acc[rr] = 0.f;
    const float* WT = ws + OFF_WINT;
    for (int k = 0; k < Dd; ++k){
      float w = WT[k*SRr + col];
      #pragma unroll
      for (int rr = 0; rr < 8; ++rr)
        acc[rr] = fmaf(xs[rowgrp*8 + rr][k], w, acc[rr]);
    }
    #pragma unroll
    for (int rr = 0; rr < 8; ++rr){
      float a = acc[rr];
      us[rowgrp*8 + rr][col] = 0.5f * a * (1.0f + erff(a * 0.70710678118654752f));
    }
  }
  __syncthreads();
  // phase 2: s[16][256] = us @ WoutT + b
  float sacc[16];
  float bv = bsh[tid];
  #pragma unroll
  for (int row = 0; row < 16; ++row) sacc[row] = bv;
  const float* WT2 = ws + OFF_WOUTT;
  for (int k = 0; k < SRr; ++k){
    float w = WT2[k*Dd + tid];
    #pragma unroll
    for (int row = 0; row < 16; ++row)
      sacc[row] = fmaf(us[row][k], w, sacc[row]);
  }
  // write S and XPT (transposed [B,D,T])
  float xp[16];
  #pragma unroll
  for (int row = 0; row < 16; ++row){
    float xv = xs[row][tid];
    float anc = (tid == 0) ? 1.0f : 0.0f;
    ws[OFF_S + (g0 + row)*Dd + tid] = sacc[row];
    xp[row] = xv - anc + sacc[row];
  }
  float* xpt = ws + OFF_XPT + (b*Dd + tid)*Tt + t0;
  #pragma unroll
  for (int q = 0; q < 4; ++q)
    *reinterpret_cast<float4*>(xpt + 4*q) = make_float4(xp[4*q], xp[4*q+1], xp[4*q+2], xp[4*q+3]);
}

// ---------------- FrFT energy weights (register FFT) ----------------
__global__ __launch_bounds__(256) void k_weights(float* ws){
  __shared__ float sre[16*272], sim[16*272];
  int tid = threadIdx.x;
  int chunk = blockIdx.x, b = blockIdx.y, z = blockIdx.z;
  int hi = tid >> 4, lo = tid & 15;
  int base = hi + 16*lo;                 // k = base + 256*r
  const float* tw4r = ws + OFF_TW4R; const float* tw4i = ws + OFF_TW4I;
  cpx twA[16], twB[16];
  #pragma unroll
  for (int p = 0; p < 16; ++p){
    int iA = tid * p;      twA[p] = {tw4r[iA], tw4i[iA]};
    int iB = 16 * lo * p;  twB[p] = {tw4r[iB], tw4i[iB]};
  }
  const float* prer = ws + OFF_PRER + z*Tt;
  const float* prei = ws + OFF_PREI + z*Tt;
  const float* pm2  = ws + OFF_PM2  + z*Tt;
  const float* Hv   = ws + OFF_H    + z*Lf*2;
  float e[16];
  #pragma unroll
  for (int r = 0; r < 16; ++r) e[r] = 0.f;
  for (int cc = 0; cc < 8; ++cc){
    int c = chunk*8 + cc;
    const float* xcol = ws + OFF_XPT + (b*Dd + c)*Tt;
    cpx x[16];
    #pragma unroll
    for (int j = 0; j < 16; ++j){
      if (j < 8){
        int t = j*256 + tid;
        float xv = xcol[t];
        x[j] = {xv * prer[t], xv * prei[t]};
      } else x[j] = {0.f, 0.f};
    }
    fft4096(x, sre, sim, twA, twB, tid, -1.f);
    #pragma unroll
    for (int r = 0; r < 16; ++r){
      int k = base + 256*r;
      cpx h{Hv[2*k], Hv[2*k+1]};
      x[r] = cmul(x[r], h);
    }
    __syncthreads();
    #pragma unroll
    for (int r = 0; r < 16; ++r){ int a = r*272 + 17*lo + hi; sre[a] = x[r].r; sim[a] = x[r].i; }
    __syncthreads();
    #pragma unroll
    for (int j = 0; j < 16; ++j){ int a = j*272 + 17*hi + lo; x[j] = {sre[a], sim[a]}; }
    fft4096(x, sre, sim, twA, twB, tid, +1.f);
    #pragma unroll
    for (int r = 0; r < 16; ++r){
      int k = base + 256*r;
      if (k >= 2047 && k < 4095){
        int t = k - 2047;
        e[r] += pm2[t] * (x[r].r*x[r].r + x[r].i*x[r].i);
      }
    }
  }
  float* Ez = ws + OFF_ESUM + (z*Bb + b)*Tt;
  #pragma unroll
  for (int r = 0; r < 16; ++r){
    int k = base + 256*r;
    if (k >= 2047 && k < 4095) atomicAdd(&Ez[k - 2047], e[r]);
  }
}

__global__ void k_wnorm(float* ws){
  __shared__ float red[4];
  int b = blockIdx.x, z = blockIdx.y, tid = threadIdx.x;
  const float* Ez = ws + OFF_ESUM + (z*Bb + b)*Tt;
  float* wz = ws + OFF_WTAB + (z*Bb + b)*Tt;
  float wr[8]; float psum = 0.f;
  #pragma unroll
  for (int k = 0; k < 8; ++k){
    float Ea = Ez[tid + k*256] * (1.0f / (float)Dd);
    wr[k] = sqrtf(Ea + 1e-6f);
    psum += wr[k];
  }
  float tot = block_reduce_sum(psum, red, tid);
  float inv = 1.0f / (tot / (float)Tt + 1e-6f);
  #pragma unroll
  for (int k = 0; k < 8; ++k) wz[tid + k*256] = wr[k] * inv;
}

// ---------------- subspace iteration ----------------
__global__ void k_vinit(float* ws){
  int id = blockIdx.x*256 + threadIdx.x;
  int r = id & (Rr-1); int d = (id >> 3) & (Dd-1);
  ws[OFF_V + id] = (d == r) ? 1.f : 0.f;
}

__global__ void k_traces(float* ws){
  __shared__ float Vl[Dd*Rr];
  int tile = blockIdx.x, b = blockIdx.y, tid = threadIdx.x;
  for (int i = tid; i < Dd*Rr; i += 256) Vl[i] = ws[OFF_V + b*Dd*Rr + i];
  __syncthreads();
  int t = tile*256 + tid;
  float acc[Rr];
  #pragma unroll
  for (int r = 0; r < Rr; ++r) acc[r] = 0.f;
  const float* xp = ws + OFF_XPT + (b*Dd)*Tt + t;
  for (int d = 0; d < Dd; ++d){
    float xv = xp[d*Tt];
    #pragma unroll
    for (int r = 0; r < Rr; ++r) acc[r] = fmaf(xv, Vl[d*Rr + r], acc[r]);
  }
  #pragma unroll
  for (int r = 0; r < Rr; ++r) ws[OFF_YT + (b*Rr + r)*Tt + t] = acc[r];
}

__global__ __launch_bounds__(256) void k_komega(float* ws){
  __shared__ float sre[16*272], sim[16*272];
  int tid = threadIdx.x;
  int rr = blockIdx.x, b = blockIdx.y, z = blockIdx.z;
  int hi = tid >> 4, lo = tid & 15;
  int base = hi + 16*lo;
  int v1 = z, v2 = z + NA;
  const float* tw4r = ws + OFF_TW4R; const float* tw4i = ws + OFF_TW4I;
  cpx twA[16], twB[16];
  #pragma unroll
  for (int p = 0; p < 16; ++p){
    int iA = tid * p;      twA[p] = {tw4r[iA], tw4i[iA]};
    int iB = 16 * lo * p;  twB[p] = {tw4r[iB], tw4i[iB]};
  }
  const float* prer1 = ws + OFF_PRER + v1*Tt; const float* prei1 = ws + OFF_PREI + v1*Tt;
  const float* posr1 = ws + OFF_POSR + v1*Tt; const float* posi1 = ws + OFF_POSI + v1*Tt;
  const float* prer2 = ws + OFF_PRER + v2*Tt; const float* prei2 = ws + OFF_PREI + v2*Tt;
  const float* posr2 = ws + OFF_POSR + v2*Tt; const float* posi2 = ws + OFF_POSI + v2*Tt;
  const float* H1 = ws + OFF_H + v1*Lf*2;
  const float* H2 = ws + OFF_H + v2*Lf*2;
  const float* wz = ws + OFF_WTAB + (z*Bb + b)*Tt;
  const float* ycol = ws + OFF_YT + (b*Rr + rr)*Tt;
  float* yac = ws + OFF_YACC + (b*Rr + rr)*Tt;
  cpx x[16];
  #pragma unroll
  for (int j = 0; j < 16; ++j){
    if (j < 8){
      int t = j*256 + tid;
      float yv = ycol[t];
      x[j] = {yv * prer1[t], yv * prei1[t]};
    } else x[j] = {0.f, 0.f};
  }
  fft4096(x, sre, sim, twA, twB, tid, -1.f);
  #pragma unroll
  for (int r = 0; r < 16; ++r){ int k = base + 256*r; cpx h{H1[2*k], H1[2*k+1]}; x[r] = cmul(x[r], h); }
  __syncthreads();
  #pragma unroll
  for (int r = 0; r < 16; ++r){ int a = r*272 + 17*lo + hi; sre[a] = x[r].r; sim[a] = x[r].i; }
  __syncthreads();
  #pragma unroll
  for (int j = 0; j < 16; ++j){ int a = j*272 + 17*hi + lo; x[j] = {sre[a], sim[a]}; }
  fft4096(x, sre, sim, twA, twB, tid, +1.f);
  __syncthreads();
  #pragma unroll
  for (int r = 0; r < 16; ++r){
    int k = base + 256*r;
    if (k >= 2047 && k < 4095){
      int t = k - 2047;
      float cr = x[r].r, ci = x[r].i;
      float wv = wz[t];
      float yar = (posr1[t]*cr - posi1[t]*ci) * wv;
      float yai = (posr1[t]*ci + posi1[t]*cr) * wv;
      float gr = yar*prer2[t] - yai*prei2[t];
      float gi = yar*prei2[t] + yai*prer2[t];
      int a = (t >> 8)*272 + 17*((t >> 4) & 15) + (t & 15);
      sre[a] = gr; sim[a] = gi;
    }
  }
  __syncthreads();
  #pragma unroll
  for (int j = 0; j < 16; ++j){
    if (j < 8){ int a = j*272 + 17*hi + lo; x[j] = {sre[a], sim[a]}; }
    else x[j] = {0.f, 0.f};
  }
  fft4096(x, sre, sim, twA, twB, tid, -1.f);
  #pragma unroll
  for (int r = 0; r < 16; ++r){ int k = base + 256*r; cpx h{H2[2*k], H2[2*k+1]}; x[r] = cmul(x[r], h); }
  __syncthreads();
  #pragma unroll
  for (int r = 0; r < 16; ++r){ int a = r*272 + 17*lo + hi; sre[a] = x[r].r; sim[a] = x[r].i; }
  __syncthreads();
  #pragma unroll
  for (int j = 0; j < 16; ++j){ int a = j*272 + 17*hi + lo; x[j] = {sre[a], sim[a]}; }
  fft4096(x, sre, sim, twA, twB, tid, +1.f);
  #pragma unroll
  for (int r = 0; r < 16; ++r){
    int k = base + 256*r;
    if (k >= 2047 && k < 4095){
      int t = k - 2047;
      atomicAdd(&yac[t], posr2[t]*x[r].r - posi2[t]*x[r].i);
    }
  }
}

__global__ void k_zm(float* ws){
  __shared__ float red[4];
  int d = blockIdx.x, b = blockIdx.y, tid = threadIdx.x;
  const float* xcol = ws + OFF_XPT + (b*Dd + d)*Tt;
  for (int r = 0; r < Rr; ++r){
    const float* ycol = ws + OFF_YACC + (b*Rr + r)*Tt;
    float p = 0.f;
    for (int t = tid; t < Tt; t += 256) p = fmaf(xcol[t], ycol[t], p);
    float tot = block_reduce_sum(p, red, tid);
    if (tid == 0){
      float zval = tot / (float)(Tt * NA);
      ws[OFF_M + (b*Dd + d)*Rr + r] = zval + EPSf * ws[OFF_V + (b*Dd + d)*Rr + r];
    }
  }
}

__global__ void k_mgs(float* ws){
  __shared__ float q[Rr][Dd];
  __shared__ float red[4];
  int b = blockIdx.x, tid = threadIdx.x;
  float m[Rr];
  #pragma unroll
  for (int r = 0; r < Rr; ++r) m[r] = ws[OFF_M + (b*Dd + tid)*Rr + r];
  for (int r = 0; r < Rr; ++r){
    float v = m[r];
    for (int j = 0; j < r; ++j){
      float dotv = block_reduce_sum(q[j][tid] * v, red, tid);
      v = fmaf(-dotv, q[j][tid], v);
    }
    float n2 = block_reduce_sum(v * v, red, tid);
    q[r][tid] = v / sqrtf(n2);
    __syncthreads();
  }
  #pragma unroll
  for (int r = 0; r < Rr; ++r) ws[OFF_V + (b*Dd + tid)*Rr + r] = q[r][tid];
}

// ---------------- fused epilogue: hbuf = traces@V^T - s + anchor; y = x + hbuf@WoT; LN ----------------
__global__ __launch_bounds__(256) void k_out(const float* x, const float* g, const float* be,
                                             float* ws, float* out){
  __shared__ float hs[16][Dd + 1];
  __shared__ float ytl[16][Rr];
  __shared__ float mv_mu[16], mv_rs[16];
  int tid = threadIdx.x;
  int g0 = blockIdx.x * 16;
  int b = g0 >> 11, t0 = g0 & (Tt - 1);
  // traces for the 16 rows
  if (tid < 128){
    int row = tid >> 3, r = tid & 7;
    ytl[row][r] = ws[OFF_YT + (b*Rr + r)*Tt + t0 + row];
  }
  float vr[Rr];
  {
    const float4* Vb = reinterpret_cast<const float4*>(ws + OFF_V + (b*Dd + tid)*Rr);
    float4 v0 = Vb[0], v1 = Vb[1];
    vr[0]=v0.x; vr[1]=v0.y; vr[2]=v0.z; vr[3]=v0.w;
    vr[4]=v1.x; vr[5]=v1.y; vr[6]=v1.z; vr[7]=v1.w;
  }
  __syncthreads();
  #pragma unroll
  for (int row = 0; row < 16; ++row){
    float acc = 0.f;
    #pragma unroll
    for (int r = 0; r < Rr; ++r) acc = fmaf(ytl[row][r], vr[r], acc);
    acc -= ws[OFF_S + (g0 + row)*Dd + tid];
    if (tid == 0) acc += 1.0f;
    hs[row][tid] = acc;
  }
  __syncthreads();
  // GEMM: y[row][col=tid] = x + hs@WoT
  float acc[16];
  #pragma unroll
  for (int row = 0; row < 16; ++row) acc[row] = x[(g0 + row)*Dd + tid];
  const float* WT = ws + OFF_WOT;
  for (int k = 0; k < Dd; ++k){
    float w = WT[k*Dd + tid];
    #pragma unroll
    for (int row = 0; row < 16; ++row)
      acc[row] = fmaf(hs[row][k], w, acc[row]);
  }
  __syncthreads();               // hs dead; reuse as ys
  #pragma unroll
  for (int row = 0; row < 16; ++row) hs[row][tid] = acc[row];
  __syncthreads();
  // LN stats: 16 threads per row
  {
    int row = tid >> 4, j = tid & 15;
    float yv[16]; float sum = 0.f;
    #pragma unroll
    for (int mth = 0; mth < 16; ++mth){ yv[mth] = hs[row][j + 16*mth]; sum += yv[mth]; }
    #pragma unroll
    for (int o = 8; o > 0; o >>= 1) sum += __shfl_xor(sum, o, 16);
    float mu = sum * (1.0f / (float)Dd);
    float ssq = 0.f;
    #pragma unroll
    for (int mth = 0; mth < 16; ++mth){ float d = yv[mth] - mu; ssq = fmaf(d, d, ssq); }
    #pragma unroll
    for (int o = 8; o > 0; o >>= 1) ssq += __shfl_xor(ssq, o, 16);
    if (j == 0){ mv_mu[row] = mu; mv_rs[row] = rsqrtf(ssq * (1.0f / (float)Dd) + 1e-5f); }
  }
  __syncthreads();
  float gg = g[tid], bb = be[tid];
  #pragma unroll
  for (int row = 0; row < 16; ++row)
    out[(g0 + row)*Dd + tid] = (acc[row] - mv_mu[row]) * mv_rs[row] * gg + bb;
}

extern "C" void kernel_launch(void* const* d_in, const int* in_sizes, int n_in,
                              void* d_out, int out_size, void* d_ws, size_t ws_size,
                              hipStream_t stream){
  (void)in_sizes; (void)n_in; (void)out_size; (void)ws_size;
  const float* x    = (const float*)d_in[0];
  const float* Win  = (const float*)d_in[1];
  const float* Wout = (const float*)d_in[2];
  const float* bsh  = (const float*)d_in[3];
  const float* Wo   = (const float*)d_in[4];
  const float* g    = (const float*)d_in[5];
  const float* be   = (const float*)d_in[6];
  float* ws  = (float*)d_ws;
  float* out = (float*)d_out;

  hipLaunchKernelGGL(k_twiddle, dim3(16), dim3(256), 0, stream, ws);
  hipLaunchKernelGGL(k_tables, dim3(NV), dim3(256), 0, stream, ws);
  hipLaunchKernelGGL(k_hfft, dim3(NV), dim3(256), 0, stream, ws);
  hipLaunchKernelGGL(k_transpose, dim3(Dd*Dd/256), dim3(256), 0, stream, Win, Wout, Wo, ws);
  hipLaunchKernelGGL(k_shift, dim3(Bb*Tt/16), dim3(256), 0, stream, x, bsh, ws);
  hipMemsetAsync(ws + OFF_ESUM, 0, (size_t)NA*Bb*Tt*sizeof(float), stream);
  hipLaunchKernelGGL(k_weights, dim3(Dd/8, Bb, NA), dim3(256), 0, stream, ws);
  hipLaunchKernelGGL(k_wnorm, dim3(Bb, NA), dim3(256), 0, stream, ws);
  hipLaunchKernelGGL(k_vinit, dim3(Bb*Dd*Rr/256), dim3(256), 0, stream, ws);
  for (int it = 0; it < 2; ++it){
    hipLaunchKernelGGL(k_traces, dim3(Tt/256, Bb), dim3(256), 0, stream, ws);
    hipMemsetAsync(ws + OFF_YACC, 0, (size_t)Bb*Rr*Tt*sizeof(float), stream);
    hipLaunchKernelGGL(k_komega, dim3(Rr, Bb, NA), dim3(256), 0, stream, ws);
    hipLaunchKernelGGL(k_zm, dim3(Dd, Bb), dim3(256), 0, stream, ws);
    hipLaunchKernelGGL(k_mgs, dim3(Bb), dim3(256), 0, stream, ws);
  }
  hipLaunchKernelGGL(k_traces, dim3(Tt/256, Bb), dim3(256), 0, stream, ws);
  hipLaunchKernelGGL(k_out, dim3(Bb*Tt/16), dim3(256), 0, stream, x, g, be, ws, out);
}